// Round 4
// baseline (382.832 us; speedup 1.0000x reference)
//
#include <hip/hip_runtime.h>
#include <math.h>

#define BB 16
#define CC 1024
#define SS 4096
#define SCH 16            // spatial positions per block (one chunk)
#define KBLK (SS / SCH)   // 256 k-blocks per batch

__device__ __forceinline__ float4 shfl_down_f4(float4 v, int d) {
    v.x = __shfl_down(v.x, d);
    v.y = __shfl_down(v.y, d);
    v.z = __shfl_down(v.z, d);
    v.w = __shfl_down(v.w, d);
    return v;
}
__device__ __forceinline__ void add4(float4& a, const float4 b) {
    a.x += b.x; a.y += b.y; a.z += b.z; a.w += b.w;
}

// v5: NCH=1 — one 16-s chunk per block, no chunk loop.
// v4 (~113us effective) was structure-bound: per chunk, the post-load serial
// section (4-deep shuffle chain + barrier + LDS readback + fold) had zero
// outstanding global loads, and next-chunk loads couldn't issue earlier
// because xv is reused by the fold. With one chunk per block, pipelining
// comes from block turnover: a retiring block's serial tail overlaps the
// next block's load burst. 4096 blocks, one __syncthreads() per block,
// ~60 live VGPRs (no np accumulator, no wred double-buffer) -> no spill
// under the 128-VGPR cap of (512,2).
__global__ __launch_bounds__(512, 2) void k_fused(
    const float* __restrict__ x, const float* __restrict__ w,
    const float* __restrict__ bias,
    float* __restrict__ Nk, float* __restrict__ sk)
{
    __shared__ float4 wred[32];    // 8 waves x 4 m

    const int kblk = blockIdx.x;   // 0..255
    const int b    = blockIdx.y;   // 0..15
    const int t    = threadIdx.x;  // 0..511
    const int wave = t >> 6;       // 0..7
    const int lane = t & 63;
    const int q    = t >> 2;       // 0..127: channel group (c = q + 128*i)
    const int m    = t & 3;        // 0..3:   s = 4m..4m+3 within chunk

    const float* xb = x + (size_t)b * CC * SS + (size_t)q * SS
                        + kblk * SCH + m * 4;

    // ---- one load burst: 8 rows x float4 per thread (64 KB per block) ----
    float4 xv[8];
#pragma unroll
    for (int i = 0; i < 8; ++i)
        xv[i] = *(const float4*)(xb + (size_t)i * 128 * SS);

    float wreg[8];
#pragma unroll
    for (int i = 0; i < 8; ++i) wreg[i] = w[q + 128 * i];
    const float bv = bias[0];

    // ---- partial logits ----
    float4 lacc = make_float4(0.f, 0.f, 0.f, 0.f);
#pragma unroll
    for (int i = 0; i < 8; ++i) {
        lacc.x += xv[i].x * wreg[i];
        lacc.y += xv[i].y * wreg[i];
        lacc.z += xv[i].z * wreg[i];
        lacc.w += xv[i].w * wreg[i];
    }

    // ---- in-wave reduce over the 16 q-slots (same m) ----
    add4(lacc, shfl_down_f4(lacc, 4));
    add4(lacc, shfl_down_f4(lacc, 8));
    add4(lacc, shfl_down_f4(lacc, 16));
    add4(lacc, shfl_down_f4(lacc, 32));
    if (lane < 4) wred[wave * 4 + lane] = lacc;   // lane == m here
    __syncthreads();

    // ---- redundant cross-wave reduce: 8 broadcast ds_read_b128 ----
    float4 r0 = wred[ 0 + m];
    float4 r1 = wred[ 4 + m];
    add4(r0, wred[ 8 + m]);
    add4(r1, wred[12 + m]);
    add4(r0, wred[16 + m]);
    add4(r1, wred[20 + m]);
    add4(r0, wred[24 + m]);
    add4(r1, wred[28 + m]);
    add4(r0, r1);

    // ---- softmax numerator weights (no-max: |logit| <~ 1, exp direct) ----
    float4 e;
    e.x = __expf((r0.x + bv) * 0.03125f);
    e.y = __expf((r0.y + bv) * 0.03125f);
    e.z = __expf((r0.z + bv) * 0.03125f);
    e.w = __expf((r0.w + bv) * 0.03125f);

    // ---- fold + epilogue fused: weighted channel sums, reduce over m ----
#pragma unroll
    for (int i = 0; i < 8; ++i) {
        float v = xv[i].x * e.x + xv[i].y * e.y
                + xv[i].z * e.z + xv[i].w * e.w;
        v += __shfl_down(v, 1);
        v += __shfl_down(v, 2);
        if (m == 0)
            Nk[((size_t)(b * KBLK + kblk)) * CC + q + 128 * i] = v;
    }

    // sum of e over this chunk's 16 s: lanes 0..3 of wave 0 hold the 4 m's
    if (t < 4) {
        float sv = (e.x + e.y) + (e.z + e.w);
        sv += __shfl_down(sv, 1);
        sv += __shfl_down(sv, 2);
        if (t == 0) sk[b * KBLK + kblk] = sv;
    }
}

// Combine: out[b,c] = (sum_k Nk[k,c]) / (sum_k sk[k]).
// 256 threads: 4 k-groups x 64 channels, LDS combine of the 4 partials.
__global__ __launch_bounds__(256) void k_combine(
    const float* __restrict__ Nk, const float* __restrict__ sk,
    float* __restrict__ out)
{
    __shared__ float part[4][64];

    const int b  = blockIdx.y;
    const int c0 = blockIdx.x * 64;
    const int t  = threadIdx.x;    // 0..255
    const int c  = t & 63;
    const int kg = t >> 6;         // 0..3

    // D: each wave redundantly reduces all 256 sk (lane loads 4)
    float sv = 0.f;
#pragma unroll
    for (int j = 0; j < 4; ++j) sv += sk[b * KBLK + (t & 63) + 64 * j];
    for (int d = 32; d; d >>= 1) sv += __shfl_xor(sv, d);
    const float D = sv;

    float acc = 0.f;
    const float* Nb = Nk + (size_t)b * KBLK * CC + (size_t)(kg * 64) * CC + c0 + c;
#pragma unroll 8
    for (int j = 0; j < 64; ++j)
        acc += Nb[(size_t)j * CC];
    part[kg][c] = acc;
    __syncthreads();

    if (t < 64)
        out[b * CC + c0 + t] =
            (part[0][t] + part[1][t] + part[2][t] + part[3][t]) / D;
}

extern "C" void kernel_launch(void* const* d_in, const int* in_sizes, int n_in,
                              void* d_out, int out_size, void* d_ws, size_t ws_size,
                              hipStream_t stream) {
    const float* x    = (const float*)d_in[0];  // [16,1024,64,64]
    const float* w    = (const float*)d_in[1];  // [1024]
    const float* bias = (const float*)d_in[2];  // [1]
    float* out = (float*)d_out;                 // [16,1024,1,1]

    float* Nk = (float*)d_ws;                           // 16*256*1024 f32 = 16 MB
    float* sk = Nk + (size_t)BB * KBLK * CC;            // 16*256 f32

    k_fused<<<dim3(KBLK, BB), 512, 0, stream>>>(x, w, bias, Nk, sk);
    k_combine<<<dim3(CC / 64, BB), 256, 0, stream>>>(Nk, sk, out);
}